// Round 5
// baseline (2138.134 us; speedup 1.0000x reference)
//
#include <hip/hip_runtime.h>
#include <math.h>

#define NITER 1000
#define LRATE 0.1f

typedef float v2f __attribute__((ext_vector_type(2)));
typedef unsigned int v2u __attribute__((ext_vector_type(2)));

__device__ __forceinline__ float rcpf(float x) { return __builtin_amdgcn_rcpf(x); }

__device__ __forceinline__ v2f dupf(float x) { v2f d = {x, x}; return d; }

// Guaranteed packed f32 math (compiler was scalarizing <2 x float> ops).
__device__ __forceinline__ v2f pk_mul(v2f a, v2f b) {
    v2f d;
    asm("v_pk_mul_f32 %0, %1, %2" : "=v"(d) : "v"(a), "v"(b));
    return d;
}
__device__ __forceinline__ v2f pk_add(v2f a, v2f b) {
    v2f d;
    asm("v_pk_add_f32 %0, %1, %2" : "=v"(d) : "v"(a), "v"(b));
    return d;
}
__device__ __forceinline__ v2f pk_fma(v2f a, v2f b, v2f c) {
    v2f d;
    asm("v_pk_fma_f32 %0, %1, %2, %3" : "=v"(d) : "v"(a), "v"(b), "v"(c));
    return d;
}

template<int CTRL>
__device__ __forceinline__ float dpp_mov(float v) {
    return __int_as_float(__builtin_amdgcn_update_dpp(0, __float_as_int(v), CTRL, 0xF, 0xF, true));
}

__device__ __forceinline__ int lane_id() {
    return __builtin_amdgcn_mbcnt_hi(~0u, __builtin_amdgcn_mbcnt_lo(~0u, 0u));
}

__device__ __forceinline__ void swap16(float& x, float& y) {
#if __has_builtin(__builtin_amdgcn_permlane16_swap)
    v2u r = __builtin_amdgcn_permlane16_swap(__float_as_uint(x), __float_as_uint(y), false, false);
    x = __uint_as_float(r[0]);
    y = __uint_as_float(r[1]);
#else
    const bool up = lane_id() & 16;
    const float send = up ? x : y;
    const float recv = __shfl_xor(send, 16);
    x = up ? recv : x;
    y = up ? y : recv;
#endif
}

__device__ __forceinline__ void swap32(float& x, float& y) {
#if __has_builtin(__builtin_amdgcn_permlane32_swap)
    v2u r = __builtin_amdgcn_permlane32_swap(__float_as_uint(x), __float_as_uint(y), false, false);
    x = __uint_as_float(r[0]);
    y = __uint_as_float(r[1]);
#else
    const bool up = lane_id() & 32;
    const float send = up ? x : y;
    const float recv = __shfl_xor(send, 32);
    x = up ? recv : x;
    y = up ? y : recv;
#endif
}

// One block, 512 threads = 8 waves (2 waves/SIMD for latency hiding).
// Wave w owns sections {2w, 2w+1}. Lane L owns freqs 8L..8L+7 (4 pairs).
__global__ __launch_bounds__(512, 2)
void sgd_filter_design_kernel(const float* __restrict__ target,
                              const float* __restrict__ sos_init,
                              float* __restrict__ out)
{
    const int t = threadIdx.x;
    const int w = t >> 6;
    const int L = t & 63;

    __shared__ __align__(16) float sosW[96];      // [w][s'][c] = 12w + 6s' + c
    __shared__ __align__(16) float wq[8][576];    // swizzled per-wave |H|^2 partials

    if (t < 96) {
        const int s = t / 6, c = t - 6 * s;
        sosW[12 * (s >> 1) + 6 * (s & 1) + c] = sos_init[t];
    }

    // Per-lane frequency constants, freqs n = 8L + 2i + h
    const float PI = 3.14159265358979323846f;
    v2f C1p[4], S1p[4], C2p[4], S2p[4], mKT[4];
    #pragma unroll
    for (int i = 0; i < 4; ++i) {
        #pragma unroll
        for (int h = 0; h < 2; ++h) {
            const int n = 8 * L + 2 * i + h;
            const float wr = PI * (float)n / 511.0f;
            const float cc = cosf(wr), ss = sinf(wr);
            C1p[i][h] = cc;
            S1p[i][h] = ss;
            C2p[i][h] = 2.0f * cc * cc - 1.0f;
            S2p[i][h] = 2.0f * ss * cc;
            mKT[i][h] = -0.03392925639869154f * target[n];
        }
    }
    const v2f KL = {0.10213724040f, 0.10213724040f};

    // swizzled wq base: pad 4 floats every 4 lanes -> <=2-way bank conflicts
    const int sw = 8 * L + 4 * (L >> 2);

    // butterfly: 16 columns, level masks [16,32,1,2], weights [8,4,2,1]
    const int col = ((L & 16) >> 1) | ((L & 32) >> 3) | ((L & 1) << 1) | ((L & 2) >> 1);
    const bool up1 = L & 1, up2 = L & 2;
    const bool is_writer = ((L & 12) == 0) && (col < 12);

    __syncthreads();

    float val_own = 0.0f;
    if (col < 12) val_own = sosW[12 * w + col];

    for (int it = 0; it < NITER; ++it) {
        float cs[12];
        #pragma unroll
        for (int r = 0; r < 3; ++r) {
            const float4 v = *reinterpret_cast<const float4*>(&sosW[12 * w + 4 * r]);
            cs[4*r+0] = v.x; cs[4*r+1] = v.y; cs[4*r+2] = v.z; cs[4*r+3] = v.w;
        }

        // ---- forward: 2 sections x 4 freq-pairs ----
        v2f Ur[2][4], Ui[2][4], Vr[2][4], Vi[2][4];
        v2f qp[4];
        qp[0] = qp[1] = qp[2] = qp[3] = dupf(1.0f);
        #pragma unroll
        for (int sp = 0; sp < 2; ++sp) {
            const v2f B0 = dupf(cs[6*sp+0]), B1 = dupf(cs[6*sp+1]), B2 = dupf(cs[6*sp+2]);
            const v2f A0 = dupf(cs[6*sp+3]), A1 = dupf(cs[6*sp+4]), A2 = dupf(cs[6*sp+5]);
            #pragma unroll
            for (int i = 0; i < 4; ++i) {
                const v2f nr = pk_fma(B2, C2p[i], pk_fma(B1, C1p[i], B0));
                const v2f ni = pk_fma(B2, S2p[i], pk_mul(B1, S1p[i]));  // -Im(num)
                const v2f dr = pk_fma(A2, C2p[i], pk_fma(A1, C1p[i], A0));
                const v2f di = pk_fma(A2, S2p[i], pk_mul(A1, S1p[i]));  // -Im(den)
                const v2f mn = pk_fma(nr, nr, pk_mul(ni, ni));
                const v2f md = pk_fma(dr, dr, pk_mul(di, di));
                v2f imn, imd;
                imn[0] = rcpf(mn[0]); imn[1] = rcpf(mn[1]);
                imd[0] = rcpf(md[0]); imd[1] = rcpf(md[1]);
                qp[i] = pk_mul(qp[i], pk_mul(mn, imd));
                Ur[sp][i] = pk_mul(nr, imn); Ui[sp][i] = pk_mul(ni, imn);
                Vr[sp][i] = pk_mul(dr, imd); Vi[sp][i] = pk_mul(di, imd);
            }
        }

        // publish this wave's partial |H|^2
        float4 q0, q1;
        q0.x = qp[0][0]; q0.y = qp[0][1]; q0.z = qp[1][0]; q0.w = qp[1][1];
        q1.x = qp[2][0]; q1.y = qp[2][1]; q1.z = qp[3][0]; q1.w = qp[3][1];
        *reinterpret_cast<float4*>(&wq[w][sw])     = q0;
        *reinterpret_cast<float4*>(&wq[w][sw + 4]) = q1;
        __syncthreads();

        // combine 8 wave-partials -> total |H|^2 per freq
        v2f qt[4];
        {
            const float4 r0 = *reinterpret_cast<const float4*>(&wq[0][sw]);
            const float4 r1 = *reinterpret_cast<const float4*>(&wq[0][sw + 4]);
            qt[0] = (v2f){r0.x, r0.y}; qt[1] = (v2f){r0.z, r0.w};
            qt[2] = (v2f){r1.x, r1.y}; qt[3] = (v2f){r1.z, r1.w};
        }
        #pragma unroll
        for (int ww = 1; ww < 8; ++ww) {
            const float4 r0 = *reinterpret_cast<const float4*>(&wq[ww][sw]);
            const float4 r1 = *reinterpret_cast<const float4*>(&wq[ww][sw + 4]);
            qt[0] = pk_mul(qt[0], (v2f){r0.x, r0.y});
            qt[1] = pk_mul(qt[1], (v2f){r0.z, r0.w});
            qt[2] = pk_mul(qt[2], (v2f){r1.x, r1.y});
            qt[3] = pk_mul(qt[3], (v2f){r1.z, r1.w});
        }

        // K per freq
        v2f Kp[4];
        #pragma unroll
        for (int i = 0; i < 4; ++i) {
            v2f lg;
            lg[0] = __log2f(qt[i][0]);
            lg[1] = __log2f(qt[i][1]);
            Kp[i] = pk_fma(lg, KL, mKT[i]);
        }

        // ---- gradient accumulate (V-side positive, negated at horiz) ----
        v2f aU0[2], aU1[2], aU2[2], aV0[2], aV1[2], aV2[2];
        #pragma unroll
        for (int sp = 0; sp < 2; ++sp) {
            #pragma unroll
            for (int i = 0; i < 4; ++i) {
                const v2f KUr = pk_mul(Kp[i], Ur[sp][i]);
                const v2f KUi = pk_mul(Kp[i], Ui[sp][i]);
                const v2f KVr = pk_mul(Kp[i], Vr[sp][i]);
                const v2f KVi = pk_mul(Kp[i], Vi[sp][i]);
                if (i == 0) {
                    aU0[sp] = KUr;
                    aU1[sp] = pk_fma(C1p[i], KUr, pk_mul(S1p[i], KUi));
                    aU2[sp] = pk_fma(C2p[i], KUr, pk_mul(S2p[i], KUi));
                    aV0[sp] = KVr;
                    aV1[sp] = pk_fma(C1p[i], KVr, pk_mul(S1p[i], KVi));
                    aV2[sp] = pk_fma(C2p[i], KVr, pk_mul(S2p[i], KVi));
                } else {
                    aU0[sp] = pk_add(aU0[sp], KUr);
                    aU1[sp] = pk_fma(C1p[i], KUr, pk_fma(S1p[i], KUi, aU1[sp]));
                    aU2[sp] = pk_fma(C2p[i], KUr, pk_fma(S2p[i], KUi, aU2[sp]));
                    aV0[sp] = pk_add(aV0[sp], KVr);
                    aV1[sp] = pk_fma(C1p[i], KVr, pk_fma(S1p[i], KVi, aV1[sp]));
                    aV2[sp] = pk_fma(C2p[i], KVr, pk_fma(S2p[i], KVi, aV2[sp]));
                }
            }
        }

        float g12[12];
        #pragma unroll
        for (int sp = 0; sp < 2; ++sp) {
            g12[6*sp+0] = aU0[sp][0] + aU0[sp][1];
            g12[6*sp+1] = aU1[sp][0] + aU1[sp][1];
            g12[6*sp+2] = aU2[sp][0] + aU2[sp][1];
            g12[6*sp+3] = -(aV0[sp][0] + aV0[sp][1]);
            g12[6*sp+4] = -(aV1[sp][0] + aV1[sp][1]);
            g12[6*sp+5] = -(aV2[sp][0] + aV2[sp][1]);
        }

        // ---- reduce-scatter: 16 cols (12 real + 4 pad) over 64 lanes ----
        float r8v[8];
        #pragma unroll
        for (int i = 0; i < 8; ++i) {            // mask 16, weight 8
            float x = g12[i];
            float y = (i + 8 < 12) ? g12[i + 8] : 0.0f;
            swap16(x, y);
            r8v[i] = x + y;
        }
        float r4v[4];
        #pragma unroll
        for (int i = 0; i < 4; ++i) {            // mask 32, weight 4
            float x = r8v[i], y = r8v[i + 4];
            swap32(x, y);
            r4v[i] = x + y;
        }
        float r2v[2];
        #pragma unroll
        for (int i = 0; i < 2; ++i) {            // mask 1 (DPP), weight 2
            const float x = r4v[i], y = r4v[i + 2];
            const float P = up1 ? y : x, Q = up1 ? x : y;
            r2v[i] = P + dpp_mov<0xB1>(Q);
        }
        float r1v;
        {                                         // mask 2 (DPP), weight 1
            const float x = r2v[0], y = r2v[1];
            const float P = up2 ? y : x, Q = up2 ? x : y;
            r1v = P + dpp_mov<0x4E>(Q);
        }
        // full-sum exchanges over remaining masks 8 and 4
        r1v += dpp_mov<0x128>(r1v);
        r1v += __shfl_xor(r1v, 4);

        if (col < 12) val_own = fmaf(-LRATE, r1v, val_own);
        if (is_writer) sosW[12 * w + col] = val_own;
        __syncthreads();
    }

    if (t < 96) {
        const int s = t / 6, c = t - 6 * s;
        out[t] = sosW[12 * (s >> 1) + 6 * (s & 1) + c];
    }
}

extern "C" void kernel_launch(void* const* d_in, const int* in_sizes, int n_in,
                              void* d_out, int out_size, void* d_ws, size_t ws_size,
                              hipStream_t stream) {
    const float* target   = (const float*)d_in[0];   // (512,)
    const float* sos_init = (const float*)d_in[1];   // (1,16,6) = 96
    float* out = (float*)d_out;                      // 96 floats
    hipLaunchKernelGGL(sgd_filter_design_kernel, dim3(1), dim3(512), 0, stream,
                       target, sos_init, out);
}

// Round 6
// 1785.701 us; speedup vs baseline: 1.1974x; 1.1974x over previous
//
#include <hip/hip_runtime.h>
#include <math.h>

#define NITER 1000
#define LRATE 0.1f

typedef float v2f __attribute__((ext_vector_type(2)));
typedef unsigned int v2u __attribute__((ext_vector_type(2)));

__device__ __forceinline__ float rcpf(float x) { return __builtin_amdgcn_rcpf(x); }
__device__ __forceinline__ v2f dupf(float x) { v2f d = {x, x}; return d; }

__device__ __forceinline__ float readlane_f(float v, int l) {
    return __int_as_float(__builtin_amdgcn_readlane(__float_as_int(v), l));
}

__device__ __forceinline__ v2f pk_mul(v2f a, v2f b) {
    v2f d;
    asm("v_pk_mul_f32 %0, %1, %2" : "=v"(d) : "v"(a), "v"(b));
    return d;
}
__device__ __forceinline__ v2f pk_add(v2f a, v2f b) {
    v2f d;
    asm("v_pk_add_f32 %0, %1, %2" : "=v"(d) : "v"(a), "v"(b));
    return d;
}
__device__ __forceinline__ v2f pk_fma(v2f a, v2f b, v2f c) {
    v2f d;
    asm("v_pk_fma_f32 %0, %1, %2, %3" : "=v"(d) : "v"(a), "v"(b), "v"(c));
    return d;
}

template<int CTRL>
__device__ __forceinline__ float dpp_mov(float v) {
    return __int_as_float(__builtin_amdgcn_update_dpp(0, __float_as_int(v), CTRL, 0xF, 0xF, true));
}

__device__ __forceinline__ int lane_id() {
    return __builtin_amdgcn_mbcnt_hi(~0u, __builtin_amdgcn_mbcnt_lo(~0u, 0u));
}

__device__ __forceinline__ void swap16(float& x, float& y) {
#if __has_builtin(__builtin_amdgcn_permlane16_swap)
    v2u r = __builtin_amdgcn_permlane16_swap(__float_as_uint(x), __float_as_uint(y), false, false);
    x = __uint_as_float(r[0]);
    y = __uint_as_float(r[1]);
#else
    const bool up = lane_id() & 16;
    const float send = up ? x : y;
    const float recv = __shfl_xor(send, 16);
    x = up ? recv : x;
    y = up ? y : recv;
#endif
}

__device__ __forceinline__ void swap32(float& x, float& y) {
#if __has_builtin(__builtin_amdgcn_permlane32_swap)
    v2u r = __builtin_amdgcn_permlane32_swap(__float_as_uint(x), __float_as_uint(y), false, false);
    x = __uint_as_float(r[0]);
    y = __uint_as_float(r[1]);
#else
    const bool up = lane_id() & 32;
    const float send = up ? x : y;
    const float recv = __shfl_xor(send, 32);
    x = up ? recv : x;
    y = up ? y : recv;
#endif
}

// One block, 1024 threads = 16 waves (4/SIMD). Wave w owns section w; its 6
// coefficients live in registers (owner lanes + readlane broadcast). Lane L
// owns freqs 8L..8L+7 (4 packed pairs). Cross-wave traffic: per-wave |H|^2
// partials (wq) and per-freq K factors (Kbuf), both chunk-swizzled
// sw = 8L + 4*(L>>2) (2-way bank aliasing = free).
__global__ __launch_bounds__(1024, 4)
void sgd_filter_design_kernel(const float* __restrict__ target,
                              const float* __restrict__ sos_init,
                              float* __restrict__ out)
{
    const int t = threadIdx.x;
    const int w = t >> 6;
    const int L = t & 63;

    __shared__ __align__(16) float wq[16][576];
    __shared__ __align__(16) float Kbuf[576];

    const float PI = 3.14159265358979323846f;
    v2f C1p[4], S1p[4], C2p[4], S2p[4];
    #pragma unroll
    for (int i = 0; i < 4; ++i) {
        #pragma unroll
        for (int h = 0; h < 2; ++h) {
            const int n = 8 * L + 2 * i + h;
            const float wr = PI * (float)n / 511.0f;
            const float cc = cosf(wr), ss = sinf(wr);
            C1p[i][h] = cc; S1p[i][h] = ss;
            C2p[i][h] = 2.0f * cc * cc - 1.0f;
            S2p[i][h] = 2.0f * ss * cc;
        }
    }

    float mKt = 0.0f;
    int kaddr = 0;
    if (t < 512) {
        mKt = -0.03392925639869154f * target[t];
        kaddr = 8 * (t >> 3) + 4 * (t >> 5) + (t & 7);
    }

    const int sw = 8 * L + 4 * (L >> 2);
    const int col = ((L & 16) >> 2) | ((L & 32) >> 4) | (L & 1);
    const bool up1 = L & 1;
    const float lrk = (col < 3) ? -LRATE : LRATE;

    float val_own = 0.0f;
    if (col < 6) val_own = sos_init[6 * w + col];

    v2f B0 = dupf(readlane_f(val_own, 0));
    v2f B1 = dupf(readlane_f(val_own, 1));
    v2f B2 = dupf(readlane_f(val_own, 32));
    v2f A0 = dupf(readlane_f(val_own, 33));
    v2f A1 = dupf(readlane_f(val_own, 16));
    v2f A2 = dupf(readlane_f(val_own, 17));

    for (int it = 0; it < NITER; ++it) {
        v2f Ur[4], Ui[4], Vr[4], Vi[4];
        float4 q0, q1;
        #pragma unroll
        for (int i = 0; i < 4; ++i) {
            const v2f nr = pk_fma(B2, C2p[i], pk_fma(B1, C1p[i], B0));
            const v2f ni = pk_fma(B2, S2p[i], pk_mul(B1, S1p[i]));
            const v2f dr = pk_fma(A2, C2p[i], pk_fma(A1, C1p[i], A0));
            const v2f di = pk_fma(A2, S2p[i], pk_mul(A1, S1p[i]));
            const v2f mn = pk_fma(nr, nr, pk_mul(ni, ni));
            const v2f md = pk_fma(dr, dr, pk_mul(di, di));
            v2f imn, imd;
            imn[0] = rcpf(mn[0]); imn[1] = rcpf(mn[1]);
            imd[0] = rcpf(md[0]); imd[1] = rcpf(md[1]);
            const v2f q = pk_mul(mn, imd);
            Ur[i] = pk_mul(nr, imn); Ui[i] = pk_mul(ni, imn);
            Vr[i] = pk_mul(dr, imd); Vi[i] = pk_mul(di, imd);
            if (i == 0)      { q0.x = q[0]; q0.y = q[1]; }
            else if (i == 1) { q0.z = q[0]; q0.w = q[1]; }
            else if (i == 2) { q1.x = q[0]; q1.y = q[1]; }
            else             { q1.z = q[0]; q1.w = q[1]; }
        }
        *reinterpret_cast<float4*>(&wq[w][sw])     = q0;
        *reinterpret_cast<float4*>(&wq[w][sw + 4]) = q1;
        __syncthreads();   // b1: wq ready; fences last iter's Kbuf reads

        if (t < 512) {
            float p[16];
            #pragma unroll
            for (int ww = 0; ww < 16; ++ww) p[ww] = wq[ww][kaddr];
            p[0] *= p[8];  p[1] *= p[9];  p[2] *= p[10]; p[3] *= p[11];
            p[4] *= p[12]; p[5] *= p[13]; p[6] *= p[14]; p[7] *= p[15];
            p[0] *= p[4];  p[1] *= p[5];  p[2] *= p[6];  p[3] *= p[7];
            p[0] *= p[2];  p[1] *= p[3];
            p[0] *= p[1];
            Kbuf[kaddr] = fmaf(__log2f(p[0]), 0.10213724040f, mKt);
        }
        __syncthreads();   // b2: Kbuf ready

        const float4 k0 = *reinterpret_cast<const float4*>(&Kbuf[sw]);
        const float4 k1 = *reinterpret_cast<const float4*>(&Kbuf[sw + 4]);
        v2f Kp[4];
        Kp[0][0] = k0.x; Kp[0][1] = k0.y; Kp[1][0] = k0.z; Kp[1][1] = k0.w;
        Kp[2][0] = k1.x; Kp[2][1] = k1.y; Kp[3][0] = k1.z; Kp[3][1] = k1.w;

        v2f a0v, a1v, a2v, a3v, a4v, a5v;
        #pragma unroll
        for (int i = 0; i < 4; ++i) {
            const v2f KUr = pk_mul(Kp[i], Ur[i]);
            const v2f KUi = pk_mul(Kp[i], Ui[i]);
            const v2f KVr = pk_mul(Kp[i], Vr[i]);
            const v2f KVi = pk_mul(Kp[i], Vi[i]);
            if (i == 0) {
                a0v = KUr;
                a1v = pk_fma(C1p[i], KUr, pk_mul(S1p[i], KUi));
                a2v = pk_fma(C2p[i], KUr, pk_mul(S2p[i], KUi));
                a3v = KVr;
                a4v = pk_fma(C1p[i], KVr, pk_mul(S1p[i], KVi));
                a5v = pk_fma(C2p[i], KVr, pk_mul(S2p[i], KVi));
            } else {
                a0v = pk_add(a0v, KUr);
                a1v = pk_fma(C1p[i], KUr, pk_fma(S1p[i], KUi, a1v));
                a2v = pk_fma(C2p[i], KUr, pk_fma(S2p[i], KUi, a2v));
                a3v = pk_add(a3v, KVr);
                a4v = pk_fma(C1p[i], KVr, pk_fma(S1p[i], KVi, a4v));
                a5v = pk_fma(C2p[i], KVr, pk_fma(S2p[i], KVi, a5v));
            }
        }
        float g6[6];
        g6[0] = a0v[0] + a0v[1]; g6[1] = a1v[0] + a1v[1]; g6[2] = a2v[0] + a2v[1];
        g6[3] = a3v[0] + a3v[1]; g6[4] = a4v[0] + a4v[1]; g6[5] = a5v[0] + a5v[1];

        float r4v[4];
        #pragma unroll
        for (int i = 0; i < 4; ++i) {            // mask 16, weight 4
            float x = g6[i];
            float y = (i + 4 < 6) ? g6[i + 4] : 0.0f;
            swap16(x, y);
            r4v[i] = x + y;
        }
        float r2v[2];
        #pragma unroll
        for (int i = 0; i < 2; ++i) {            // mask 32, weight 2
            float x = r4v[i], y = r4v[i + 2];
            swap32(x, y);
            r2v[i] = x + y;
        }
        float r1v;
        {                                         // mask 1 (DPP), weight 1
            const float x = r2v[0], y = r2v[1];
            const float P = up1 ? y : x, Q = up1 ? x : y;
            r1v = P + dpp_mov<0xB1>(Q);
        }
        r1v += dpp_mov<0x4E>(r1v);
        r1v += dpp_mov<0x128>(r1v);
        r1v += __shfl_xor(r1v, 4);

        val_own = fmaf(lrk, r1v, val_own);
        B0 = dupf(readlane_f(val_own, 0));
        B1 = dupf(readlane_f(val_own, 1));
        B2 = dupf(readlane_f(val_own, 32));
        A0 = dupf(readlane_f(val_own, 33));
        A1 = dupf(readlane_f(val_own, 16));
        A2 = dupf(readlane_f(val_own, 17));
    }

    if ((L & 14) == 0 && col < 6) out[6 * w + col] = val_own;
}

extern "C" void kernel_launch(void* const* d_in, const int* in_sizes, int n_in,
                              void* d_out, int out_size, void* d_ws, size_t ws_size,
                              hipStream_t stream) {
    const float* target   = (const float*)d_in[0];   // (512,)
    const float* sos_init = (const float*)d_in[1];   // (1,16,6) = 96
    float* out = (float*)d_out;                      // 96 floats
    hipLaunchKernelGGL(sgd_filter_design_kernel, dim3(1), dim3(1024), 0, stream,
                       target, sos_init, out);
}